// Round 8
// baseline (716.610 us; speedup 1.0000x reference)
//
#include <hip/hip_runtime.h>

constexpr int NN  = 50000;
constexpr int EE  = 800000;
constexpr int GG  = 64;
constexpr int LL  = 3;

__device__ __forceinline__ float reluf(float x) { return x > 0.f ? x : 0.f; }

// bf16 helpers (RTN conversion; accumulation always fp32)
__device__ __forceinline__ unsigned short f2bf(float v) {
    unsigned u = __float_as_uint(v);
    u = (u + 0x7FFFu + ((u >> 16) & 1u)) >> 16;
    return (unsigned short)u;
}
__device__ __forceinline__ float bf2f(unsigned short h) {
    return __uint_as_float((unsigned)h << 16);
}

// -------- in-degree count; also record each edge's within-row rank -----------
// (r5 lesson: keep the rank atomic HERE, where its return feeds a coalesced
// rel store; putting it in k_fill serializes atomic->scatter = 50us.)
__global__ void k_count(const int* __restrict__ ei, int* __restrict__ cnt,
                        int* __restrict__ rel) {
    int e = blockIdx.x * blockDim.x + threadIdx.x;
    if (e >= EE) return;
    rel[e] = atomicAdd(&cnt[ei[EE + e]], 1);
}

// ------- parallel exclusive scan (49 blocks x 1024) + fused per-graph degmax -
// also produces g_cnt (nodes per graph) via the same batch walk
__global__ void k_scan1(const int* __restrict__ cnt, int* __restrict__ off,
                        int* __restrict__ bsum,
                        const int* __restrict__ batch, const float* __restrict__ degree,
                        unsigned* __restrict__ degmax_u, int* __restrict__ g_cnt) {
    __shared__ int s[256];
    __shared__ unsigned smax[GG];
    __shared__ int scnt[GG];
    int t = threadIdx.x, blk = blockIdx.x;
    if (t < GG) { smax[t] = 0u; scnt[t] = 0; }
    int base = blk * 1024 + t * 4;
    int v[4], tot = 0;
#pragma unroll
    for (int j = 0; j < 4; j++) {
        int i = base + j;
        v[j] = (i < NN) ? cnt[i] : 0;
        tot += v[j];
    }
    s[t] = tot;
    __syncthreads();
    {
        int curb = -1; unsigned cur = 0u; int ccnt = 0;
#pragma unroll
        for (int j = 0; j < 4; j++) {
            int i = base + j;
            if (i < NN) {
                int b = batch[i];
                unsigned d = __float_as_uint(degree[i]);  // degree >= 0
                if (b != curb) {
                    if (curb >= 0) { atomicMax(&smax[curb], cur); atomicAdd(&scnt[curb], ccnt); }
                    curb = b; cur = d; ccnt = 1;
                } else {
                    if (d > cur) cur = d;
                    ccnt++;
                }
            }
        }
        if (curb >= 0) { atomicMax(&smax[curb], cur); atomicAdd(&scnt[curb], ccnt); }
    }
    for (int d = 1; d < 256; d <<= 1) {
        int a = (t >= d) ? s[t - d] : 0;
        __syncthreads();
        s[t] += a;
        __syncthreads();
    }
    int run = s[t] - tot;
#pragma unroll
    for (int j = 0; j < 4; j++) {
        int i = base + j;
        if (i <= NN) off[i] = run;
        run += v[j];
    }
    if (t == 255) bsum[blk] = s[255];
    __syncthreads();
    if (t < GG) {
        if (smax[t] != 0u) atomicMax(&degmax_u[t], smax[t]);
        if (scnt[t] != 0)  atomicAdd(&g_cnt[t], scnt[t]);
    }
}
// scan2 folded into scan3: each block's 256 nodes lie within ONE 1024-node
// scan1 chunk, so thread 0 computes the <=49 term bsum prefix directly.
__global__ void k_scan3(int* __restrict__ off, const int* __restrict__ bsum) {
    __shared__ int sadd;
    if (threadIdx.x == 0) {
        int chunk = blockIdx.x >> 2;
        int run = 0;
        for (int b = 0; b < chunk; b++) run += bsum[b];
        sadd = run;
    }
    __syncthreads();
    int i = blockIdx.x * blockDim.x + threadIdx.x;
    if (i <= NN) off[i] += sadd;
}

// ---------------- scatter edges into CSR order (atomic-free) -----------------
// r7: PACKED edge record, 4B/edge: [bf16(ea) | col16]. col < 65536 (NN=50000).
// Halves the edge-stream bytes for k_fill write + 4 downstream reads.
__global__ void k_fill(const int* __restrict__ ei, const float* __restrict__ ea,
                       const int* __restrict__ off, const int* __restrict__ rel,
                       unsigned* __restrict__ sorted) {
    int e = blockIdx.x * blockDim.x + threadIdx.x;
    if (e >= EE) return;
    int col = ei[e];
    int row = ei[EE + e];
    unsigned pk = ((unsigned)f2bf(ea[e]) << 16) | (unsigned)(col & 0xFFFF);
    sorted[off[row] + rel[e]] = pk;
}

// ---------------- ne_sum from CSR: 8 lanes per node, 4-way unroll ------------
__global__ void k_nesum(const float* __restrict__ x, const unsigned* __restrict__ sorted,
                        const int* __restrict__ off, float* __restrict__ ne_sum) {
    int gwave = (blockIdx.x * blockDim.x + threadIdx.x) >> 6;
    int lane = threadIdx.x & 63;
    int sub = lane >> 3;   // 8 nodes per wave
    int f = lane & 7;      // 8 features (7 x + 1 ea)
    int node = gwave * 8 + sub;
    if (node >= NN) return;
    int jb = off[node], je = off[node + 1];
    float a0 = 0.f, a1 = 0.f, a2 = 0.f, a3 = 0.f;
    int j = jb;
    for (; j + 4 <= je; j += 4) {
        unsigned p0 = sorted[j],     p1 = sorted[j + 1];
        unsigned p2 = sorted[j + 2], p3 = sorted[j + 3];
        a0 += (f < 7) ? x[(size_t)(p0 & 0xFFFFu) * 7 + f] : __uint_as_float(p0 & 0xFFFF0000u);
        a1 += (f < 7) ? x[(size_t)(p1 & 0xFFFFu) * 7 + f] : __uint_as_float(p1 & 0xFFFF0000u);
        a2 += (f < 7) ? x[(size_t)(p2 & 0xFFFFu) * 7 + f] : __uint_as_float(p2 & 0xFFFF0000u);
        a3 += (f < 7) ? x[(size_t)(p3 & 0xFFFFu) * 7 + f] : __uint_as_float(p3 & 0xFFFF0000u);
    }
    for (; j < je; j++) {
        unsigned p = sorted[j];
        a0 += (f < 7) ? x[(size_t)(p & 0xFFFFu) * 7 + f] : __uint_as_float(p & 0xFFFF0000u);
    }
    ne_sum[(size_t)node * 8 + f] = (a0 + a1) + (a2 + a3);
}

// ---------------- node pre: x_emb (fp32 + bf16 shadow) + FUSED x_agg_emb -----
__global__ __launch_bounds__(256) void k_node_pre(
        const float* __restrict__ x, const int* __restrict__ cnt,
        const float* __restrict__ ne_sum, const unsigned* __restrict__ degmax_u,
        const int* __restrict__ batch,
        const float* __restrict__ W_en, const float* __restrict__ b_en,
        const float* __restrict__ W_ene, const float* __restrict__ b_ene,
        const float* __restrict__ W_agg, const float* __restrict__ b_agg,
        float* __restrict__ x_emb, unsigned short* __restrict__ xh,
        float* __restrict__ xae) {
    __shared__ float sWen[7 * 64], sben[64];
    __shared__ float sWene[8 * 63], sbene[63];
    __shared__ float srow[4][64];
    for (int i = threadIdx.x; i < 7 * 64; i += 256) sWen[i] = W_en[i];
    for (int i = threadIdx.x; i < 64; i += 256) sben[i] = b_en[i];
    for (int i = threadIdx.x; i < 8 * 63; i += 256) sWene[i] = W_ene[i];
    for (int i = threadIdx.x; i < 63; i += 256) sbene[i] = b_ene[i];
    __syncthreads();
    int lane = threadIdx.x & 63;
    int slot = threadIdx.x >> 6;
    int wave = blockIdx.x * 4 + slot;
    int nw = gridDim.x * 4;
    float wagg[64];
#pragma unroll
    for (int k = 0; k < 64; k++) wagg[k] = W_agg[(size_t)k * 64 + lane];
    float bagg = b_agg[lane];
    for (int i = wave; i < NN; i += nw) {
        float acc = sben[lane];
#pragma unroll
        for (int k = 0; k < 7; k++) acc += x[(size_t)i * 7 + k] * sWen[k * 64 + lane];
        float xe = reluf(acc);
        x_emb[(size_t)i * 64 + lane] = xe;
        xh[(size_t)i * 64 + lane] = f2bf(xe);
        float c = (float)cnt[i]; if (c < 1.f) c = 1.f;
        float rc = 1.f / c;
        int oo = lane < 63 ? lane : 0;
        float4 n0 = *(const float4*)(ne_sum + (size_t)i * 8);
        float4 n1 = *(const float4*)(ne_sum + (size_t)i * 8 + 4);
        float na = sbene[oo];
        na += (n0.x * rc) * sWene[0 * 63 + oo];
        na += (n0.y * rc) * sWene[1 * 63 + oo];
        na += (n0.z * rc) * sWene[2 * 63 + oo];
        na += (n0.w * rc) * sWene[3 * 63 + oo];
        na += (n1.x * rc) * sWene[4 * 63 + oo];
        na += (n1.y * rc) * sWene[5 * 63 + oo];
        na += (n1.z * rc) * sWene[6 * 63 + oo];
        na += (n1.w * rc) * sWene[7 * 63 + oo];
        na = reluf(na);
        float dn = __uint_as_float(degmax_u[batch[i]]);
        float val = (lane < 63) ? na : dn;   // agg_in row, lane-distributed
        srow[slot][lane] = val;              // same-wave stage (k_mv64 idiom)
        const float* rp = &srow[slot][0];
        float a0 = bagg, a1 = 0.f;
#pragma unroll
        for (int kb = 0; kb < 64; kb += 8) {
            float4 x0 = *(const float4*)(rp + kb);
            float4 x1 = *(const float4*)(rp + kb + 4);
            a0 = fmaf(x0.x, wagg[kb + 0], a0); a1 = fmaf(x0.y, wagg[kb + 1], a1);
            a0 = fmaf(x0.z, wagg[kb + 2], a0); a1 = fmaf(x0.w, wagg[kb + 3], a1);
            a0 = fmaf(x1.x, wagg[kb + 4], a0); a1 = fmaf(x1.y, wagg[kb + 5], a1);
            a0 = fmaf(x1.z, wagg[kb + 6], a0); a1 = fmaf(x1.w, wagg[kb + 7], a1);
        }
        xae[(size_t)i * 64 + lane] = reluf(a0 + a1);
    }
}

// ---------------- fused K=128 matvec: relu([A|B] @ W + b) --------------------
// WRH: also emit bf16 shadow of output (feeds next layer's gather).
// FINAL: fuse graph-sum (batch-sorted run tracking) AND readout node-dot
//   ndot[n] = sum_lane r*W_r[64+lane] (butterfly); final fp32 row NOT stored.
template <int FINAL, int WRH>
__global__ __launch_bounds__(256, 3) void k_mv128(
        const float* __restrict__ inA, const float* __restrict__ inB,
        const float* __restrict__ W, const float* __restrict__ b,
        float* __restrict__ out, unsigned short* __restrict__ outh, int nwaves,
        const int* __restrict__ batch, float* __restrict__ g_sum,
        const float* __restrict__ W_r, float* __restrict__ ndot) {
    __shared__ float sbuf[4][2][128];
    int slot = threadIdx.x >> 6;
    int gwave = (blockIdx.x * blockDim.x + threadIdx.x) >> 6;
    int lane = threadIdx.x & 63;
    int per = (NN + nwaves - 1) / nwaves;
    int n0 = gwave * per;
    int n1 = n0 + per; if (n1 > NN) n1 = NN;
    if (n0 >= n1) return;
    float w[128];
#pragma unroll
    for (int k = 0; k < 128; k++) w[k] = W[(size_t)k * 64 + lane];
    float bias = b[lane];
    float wr = FINAL ? W_r[64 + lane] : 0.f;
    sbuf[slot][0][lane]      = inA[(size_t)n0 * 64 + lane];
    sbuf[slot][0][64 + lane] = inB[(size_t)n0 * 64 + lane];
    int cntn = n1 - n0;
    float gacc = 0.f;
    int curb = FINAL ? batch[n0] : 0;
    for (int i = 0; i < cntn; i++) {
        int n = n0 + i;
        float vA = 0.f, vB = 0.f;
        if (i + 1 < cntn) {
            vA = inA[(size_t)(n + 1) * 64 + lane];
            vB = inB[(size_t)(n + 1) * 64 + lane];
        }
        const float* bufp = &sbuf[slot][i & 1][0];
        float a0 = 0.f, a1 = 0.f;
#pragma unroll
        for (int kb = 0; kb < 128; kb += 8) {
            float4 x0 = *(const float4*)(bufp + kb);
            float4 x1 = *(const float4*)(bufp + kb + 4);
            a0 = fmaf(x0.x, w[kb + 0], a0); a1 = fmaf(x0.y, w[kb + 1], a1);
            a0 = fmaf(x0.z, w[kb + 2], a0); a1 = fmaf(x0.w, w[kb + 3], a1);
            a0 = fmaf(x1.x, w[kb + 4], a0); a1 = fmaf(x1.y, w[kb + 5], a1);
            a0 = fmaf(x1.z, w[kb + 6], a0); a1 = fmaf(x1.w, w[kb + 7], a1);
        }
        float r = reluf(a0 + a1 + bias);
        if (!FINAL) out[(size_t)n * 64 + lane] = r;
        if (WRH) outh[(size_t)n * 64 + lane] = f2bf(r);
        if (FINAL) {
            int bb = batch[n];
            if (bb != curb) {
                unsafeAtomicAdd(&g_sum[curb * 64 + lane], gacc);
                gacc = 0.f; curb = bb;
            }
            gacc += r;
            float v = r * wr;
#pragma unroll
            for (int d = 1; d < 64; d <<= 1) v += __shfl_xor(v, d, 64);
            if (lane == 0) ndot[n] = v;
        }
        if (i + 1 < cntn) {
            sbuf[slot][(i + 1) & 1][lane]      = vA;
            sbuf[slot][(i + 1) & 1][64 + lane] = vB;
        }
    }
    if (FINAL) unsafeAtomicAdd(&g_sum[curb * 64 + lane], gacc);
}

// -------- layer aggregation: x_agg = mean_j ea_j * xemb[col_j] ---------------
// r0-proven 8-wide inner structure; r4-proven one node per wave;
// r6-proven bf16 shadow gathers; r7: 4B packed edge records.
__global__ __launch_bounds__(256) void k_layer_agg(
        const unsigned short* __restrict__ xembh, const int* __restrict__ off,
        const int* __restrict__ cnt, const unsigned* __restrict__ sorted,
        float* __restrict__ xagg) {
    int lane = threadIdx.x & 63;
    int i = (blockIdx.x * blockDim.x + threadIdx.x) >> 6;   // node == wave id
    if (i >= NN) return;
    {
        int jb = off[i], je = off[i + 1];
        float a0 = 0.f, a1 = 0.f, a2 = 0.f, a3 = 0.f;
        float a4 = 0.f, a5 = 0.f, a6 = 0.f, a7 = 0.f;
        int j = jb;
        for (; j + 8 <= je; j += 8) {
            unsigned p0 = sorted[j + 0], p1 = sorted[j + 1];
            unsigned p2 = sorted[j + 2], p3 = sorted[j + 3];
            unsigned p4 = sorted[j + 4], p5 = sorted[j + 5];
            unsigned p6 = sorted[j + 6], p7 = sorted[j + 7];
            a0 = fmaf(__uint_as_float(p0 & 0xFFFF0000u), bf2f(xembh[(size_t)(p0 & 0xFFFFu) * 64 + lane]), a0);
            a1 = fmaf(__uint_as_float(p1 & 0xFFFF0000u), bf2f(xembh[(size_t)(p1 & 0xFFFFu) * 64 + lane]), a1);
            a2 = fmaf(__uint_as_float(p2 & 0xFFFF0000u), bf2f(xembh[(size_t)(p2 & 0xFFFFu) * 64 + lane]), a2);
            a3 = fmaf(__uint_as_float(p3 & 0xFFFF0000u), bf2f(xembh[(size_t)(p3 & 0xFFFFu) * 64 + lane]), a3);
            a4 = fmaf(__uint_as_float(p4 & 0xFFFF0000u), bf2f(xembh[(size_t)(p4 & 0xFFFFu) * 64 + lane]), a4);
            a5 = fmaf(__uint_as_float(p5 & 0xFFFF0000u), bf2f(xembh[(size_t)(p5 & 0xFFFFu) * 64 + lane]), a5);
            a6 = fmaf(__uint_as_float(p6 & 0xFFFF0000u), bf2f(xembh[(size_t)(p6 & 0xFFFFu) * 64 + lane]), a6);
            a7 = fmaf(__uint_as_float(p7 & 0xFFFF0000u), bf2f(xembh[(size_t)(p7 & 0xFFFFu) * 64 + lane]), a7);
        }
        if (j < je) {   // masked tail: 1-7 edges, all gathers independent
            int jl = je - 1;
            unsigned p0 = sorted[j + 0];
            unsigned p1 = sorted[min(j + 1, jl)];
            unsigned p2 = sorted[min(j + 2, jl)];
            unsigned p3 = sorted[min(j + 3, jl)];
            unsigned p4 = sorted[min(j + 4, jl)];
            unsigned p5 = sorted[min(j + 5, jl)];
            unsigned p6 = sorted[min(j + 6, jl)];
            unsigned p7 = sorted[min(j + 7, jl)];
            float s0 = __uint_as_float(p0 & 0xFFFF0000u);
            float s1 = (j + 1 < je) ? __uint_as_float(p1 & 0xFFFF0000u) : 0.f;
            float s2 = (j + 2 < je) ? __uint_as_float(p2 & 0xFFFF0000u) : 0.f;
            float s3 = (j + 3 < je) ? __uint_as_float(p3 & 0xFFFF0000u) : 0.f;
            float s4 = (j + 4 < je) ? __uint_as_float(p4 & 0xFFFF0000u) : 0.f;
            float s5 = (j + 5 < je) ? __uint_as_float(p5 & 0xFFFF0000u) : 0.f;
            float s6 = (j + 6 < je) ? __uint_as_float(p6 & 0xFFFF0000u) : 0.f;
            float s7 = (j + 7 < je) ? __uint_as_float(p7 & 0xFFFF0000u) : 0.f;
            a0 = fmaf(s0, bf2f(xembh[(size_t)(p0 & 0xFFFFu) * 64 + lane]), a0);
            a1 = fmaf(s1, bf2f(xembh[(size_t)(p1 & 0xFFFFu) * 64 + lane]), a1);
            a2 = fmaf(s2, bf2f(xembh[(size_t)(p2 & 0xFFFFu) * 64 + lane]), a2);
            a3 = fmaf(s3, bf2f(xembh[(size_t)(p3 & 0xFFFFu) * 64 + lane]), a3);
            a4 = fmaf(s4, bf2f(xembh[(size_t)(p4 & 0xFFFFu) * 64 + lane]), a4);
            a5 = fmaf(s5, bf2f(xembh[(size_t)(p5 & 0xFFFFu) * 64 + lane]), a5);
            a6 = fmaf(s6, bf2f(xembh[(size_t)(p6 & 0xFFFFu) * 64 + lane]), a6);
            a7 = fmaf(s7, bf2f(xembh[(size_t)(p7 & 0xFFFFu) * 64 + lane]), a7);
        }
        float acc = ((a0 + a1) + (a2 + a3)) + ((a4 + a5) + (a6 + a7));
        float c = (float)cnt[i]; if (c < 1.f) c = 1.f;
        xagg[(size_t)i * 64 + lane] = acc * (1.f / c);
    }
}

// ------- graph embedding: g_agg = mean @ W_g + b_g, then fused readout dot ---
__global__ void k_graph_emb(const float* __restrict__ g_sum, const int* __restrict__ g_cnt,
                            const float* __restrict__ W_g, const float* __restrict__ b_g,
                            const float* __restrict__ W_r, float* __restrict__ dotA) {
    __shared__ float sin[4 * 64];
    int lane = threadIdx.x & 63;
    int slot = threadIdx.x >> 6;
    int g = blockIdx.x * 4 + slot;
    if (g >= GG) return;
    float c = (float)g_cnt[g]; if (c < 1.f) c = 1.f;
    sin[slot * 64 + lane] = g_sum[g * 64 + lane] * (1.f / c);
    __syncthreads();
    float acc = b_g[lane];
    for (int k = 0; k < 64; k++) acc += sin[slot * 64 + k] * W_g[k * 64 + lane];
    float v = reluf(acc) * W_r[lane];
#pragma unroll
    for (int d = 1; d < 64; d <<= 1) v += __shfl_xor(v, d, 64);
    if (lane == 0) dotA[g] = v;
}

// ---------------- readout: q = dotA[batch] + ndot + b_r ----------------------
__global__ void k_readout(const float* __restrict__ dotA, const float* __restrict__ ndot,
                          const int* __restrict__ batch,
                          const float* __restrict__ b_r, float* __restrict__ out) {
    int i = blockIdx.x * blockDim.x + threadIdx.x;
    if (i >= NN) return;
    out[i] = b_r[0] + dotA[batch[i]] + ndot[i];
}

extern "C" void kernel_launch(void* const* d_in, const int* in_sizes, int n_in,
                              void* d_out, int out_size, void* d_ws, size_t ws_size,
                              hipStream_t stream) {
    const float* x      = (const float*)d_in[0];
    const int*   ei     = (const int*)d_in[1];
    const float* ea     = (const float*)d_in[2];
    const int*   batch  = (const int*)d_in[3];
    const float* degree = (const float*)d_in[4];
    const float* W_en  = (const float*)d_in[6];
    const float* b_en  = (const float*)d_in[7];
    const float* W_ene = (const float*)d_in[8];
    const float* b_ene = (const float*)d_in[9];
    const float* W_agg = (const float*)d_in[10];
    const float* b_agg = (const float*)d_in[11];
    const float* Wm    = (const float*)d_in[12];
    const float* bm    = (const float*)d_in[13];
    const float* Wu    = (const float*)d_in[14];
    const float* bu    = (const float*)d_in[15];
    const float* W_g   = (const float*)d_in[16];
    const float* b_g   = (const float*)d_in[17];
    const float* W_r   = (const float*)d_in[18];
    const float* b_r   = (const float*)d_in[19];
    float* out = (float*)d_out;

    // workspace layout (4B element offsets); zeroed region first
    char* ws = (char*)d_ws;
    size_t o = 0;
    int*      cnt      = (int*)(ws + o * 4);      o += NN;
    unsigned* degmax_u = (unsigned*)(ws + o * 4); o += GG;
    float*    g_sum    = (float*)(ws + o * 4);    o += GG * 64;
    int*      g_cnt    = (int*)(ws + o * 4);      o += GG;
    size_t zero_bytes = o * 4;
    int*      off      = (int*)(ws + o * 4);      o += NN + 1;
    int*      bsum     = (int*)(ws + o * 4);      o += 64;
    int*      rel      = (int*)(ws + o * 4);      o += EE;
    float*    ne_sum   = (float*)(ws + o * 4);    o += (size_t)NN * 8;
    unsigned* sorted   = (unsigned*)(ws + o * 4); o += EE;          // packed 4B/edge
    unsigned short* xh = (unsigned short*)(ws + o * 4); o += (size_t)NN * 32;  // bf16 shadow
    float*    xae      = (float*)(ws + o * 4);    o += (size_t)NN * 64;
    float*    xA       = (float*)(ws + o * 4);    o += (size_t)NN * 64;
    float*    xB       = (float*)(ws + o * 4);    o += (size_t)NN * 64;
    float*    xagg     = (float*)(ws + o * 4);    o += (size_t)NN * 64;
    float*    mbuf     = (float*)(ws + o * 4);    o += (size_t)NN * 64;
    float*    ndot     = (float*)(ws + o * 4);    o += NN;
    float*    dotA     = (float*)(ws + o * 4);    o += GG;

    hipMemsetAsync(d_ws, 0, zero_bytes, stream);

    const int NB_SCAN = 49;        // ceil(50001/1024)
    const int MV_BLOCKS = 768;     // 3072 waves = 3/SIMD resident, 17 nodes/wave
    const int MV_WAVES = MV_BLOCKS * 4;
    k_count<<<(EE + 255) / 256, 256, 0, stream>>>(ei, cnt, rel);
    k_scan1<<<NB_SCAN, 256, 0, stream>>>(cnt, off, bsum, batch, degree, degmax_u, g_cnt);
    k_scan3<<<(NN + 256) / 256, 256, 0, stream>>>(off, bsum);
    k_fill<<<(EE + 255) / 256, 256, 0, stream>>>(ei, ea, off, rel, sorted);
    k_nesum<<<((NN + 7) / 8 * 64 + 255) / 256, 256, 0, stream>>>(x, sorted, off, ne_sum);
    // node pre produces x_agg_emb directly (W_agg fused) + bf16 shadow of x_emb
    k_node_pre<<<1024, 256, 0, stream>>>(x, cnt, ne_sum, degmax_u, batch,
                                         W_en, b_en, W_ene, b_ene, W_agg, b_agg,
                                         xA, xh, xae);
    const float* cur = xA;
    float* nxt = xB;
    const int AGG_BLOCKS = (NN * 64 + 255) / 256;   // one node per wave
    for (int l = 0; l < LL; l++) {
        const float* WmL = Wm + (size_t)l * 128 * 64;
        const float* WuL = Wu + (size_t)l * 128 * 64;
        k_layer_agg<<<AGG_BLOCKS, 256, 0, stream>>>(xh, off, cnt, sorted, xagg);
        // m = relu([xagg|xae] @ Wm + bm)   -- single fused K=128 pass
        k_mv128<0, 0><<<MV_BLOCKS, 256, 0, stream>>>(xagg, xae, WmL, bm + l * 64,
                                                     mbuf, nullptr, MV_WAVES,
                                                     nullptr, nullptr, nullptr, nullptr);
        // x' = relu([xemb|m] @ Wu + bu)    -- single fused K=128 pass
        if (l < LL - 1) {
            // also refresh the bf16 shadow for the next layer's gather
            k_mv128<0, 1><<<MV_BLOCKS, 256, 0, stream>>>(cur, mbuf, WuL, bu + l * 64,
                                                         nxt, xh, MV_WAVES,
                                                         nullptr, nullptr, nullptr, nullptr);
        } else {
            // final layer: fuse graph-sum + readout node-dot; no fp32 row store
            k_mv128<1, 0><<<MV_BLOCKS, 256, 0, stream>>>(cur, mbuf, WuL, bu + l * 64,
                                                         nullptr, nullptr, MV_WAVES,
                                                         batch, g_sum, W_r, ndot);
        }
        float* t = (float*)cur; cur = nxt; nxt = t;
    }
    k_graph_emb<<<16, 256, 0, stream>>>(g_sum, g_cnt, W_g, b_g, W_r, dotA);
    k_readout<<<(NN + 255) / 256, 256, 0, stream>>>(dotA, ndot, batch, b_r, out);
}

// Round 9
// 398.692 us; speedup vs baseline: 1.7974x; 1.7974x over previous
//
#include <hip/hip_runtime.h>

constexpr int NN  = 50000;
constexpr int EE  = 800000;
constexpr int GG  = 64;
constexpr int LL  = 3;

__device__ __forceinline__ float reluf(float x) { return x > 0.f ? x : 0.f; }

// bf16 helpers (RTN conversion; accumulation always fp32)
__device__ __forceinline__ unsigned short f2bf(float v) {
    unsigned u = __float_as_uint(v);
    u = (u + 0x7FFFu + ((u >> 16) & 1u)) >> 16;
    return (unsigned short)u;
}
__device__ __forceinline__ float bf2f(unsigned short h) {
    return __uint_as_float((unsigned)h << 16);
}

// -------- in-degree count; also record each edge's within-row rank -----------
// (r5 lesson: keep the rank atomic HERE, where its return feeds a coalesced
// rel store; putting it in k_fill serializes atomic->scatter = 50us.)
__global__ void k_count(const int* __restrict__ ei, int* __restrict__ cnt,
                        int* __restrict__ rel) {
    int e = blockIdx.x * blockDim.x + threadIdx.x;
    if (e >= EE) return;
    rel[e] = atomicAdd(&cnt[ei[EE + e]], 1);
}

// ------- parallel exclusive scan (49 blocks x 1024) + fused per-graph degmax -
// also produces g_cnt (nodes per graph) via the same batch walk
__global__ void k_scan1(const int* __restrict__ cnt, int* __restrict__ off,
                        int* __restrict__ bsum,
                        const int* __restrict__ batch, const float* __restrict__ degree,
                        unsigned* __restrict__ degmax_u, int* __restrict__ g_cnt) {
    __shared__ int s[256];
    __shared__ unsigned smax[GG];
    __shared__ int scnt[GG];
    int t = threadIdx.x, blk = blockIdx.x;
    if (t < GG) { smax[t] = 0u; scnt[t] = 0; }
    int base = blk * 1024 + t * 4;
    int v[4], tot = 0;
#pragma unroll
    for (int j = 0; j < 4; j++) {
        int i = base + j;
        v[j] = (i < NN) ? cnt[i] : 0;
        tot += v[j];
    }
    s[t] = tot;
    __syncthreads();
    {
        int curb = -1; unsigned cur = 0u; int ccnt = 0;
#pragma unroll
        for (int j = 0; j < 4; j++) {
            int i = base + j;
            if (i < NN) {
                int b = batch[i];
                unsigned d = __float_as_uint(degree[i]);  // degree >= 0
                if (b != curb) {
                    if (curb >= 0) { atomicMax(&smax[curb], cur); atomicAdd(&scnt[curb], ccnt); }
                    curb = b; cur = d; ccnt = 1;
                } else {
                    if (d > cur) cur = d;
                    ccnt++;
                }
            }
        }
        if (curb >= 0) { atomicMax(&smax[curb], cur); atomicAdd(&scnt[curb], ccnt); }
    }
    for (int d = 1; d < 256; d <<= 1) {
        int a = (t >= d) ? s[t - d] : 0;
        __syncthreads();
        s[t] += a;
        __syncthreads();
    }
    int run = s[t] - tot;
#pragma unroll
    for (int j = 0; j < 4; j++) {
        int i = base + j;
        if (i <= NN) off[i] = run;
        run += v[j];
    }
    if (t == 255) bsum[blk] = s[255];
    __syncthreads();
    if (t < GG) {
        if (smax[t] != 0u) atomicMax(&degmax_u[t], smax[t]);
        if (scnt[t] != 0)  atomicAdd(&g_cnt[t], scnt[t]);
    }
}
// scan2 folded into scan3: each block's 256 nodes lie within ONE 1024-node
// scan1 chunk, so thread 0 computes the <=49 term bsum prefix directly.
__global__ void k_scan3(int* __restrict__ off, const int* __restrict__ bsum) {
    __shared__ int sadd;
    if (threadIdx.x == 0) {
        int chunk = blockIdx.x >> 2;
        int run = 0;
        for (int b = 0; b < chunk; b++) run += bsum[b];
        sadd = run;
    }
    __syncthreads();
    int i = blockIdx.x * blockDim.x + threadIdx.x;
    if (i <= NN) off[i] += sadd;
}

// ---------------- scatter edges into CSR order (atomic-free) -----------------
// r7-kept: PACKED edge record, 4B/edge: [bf16(ea) | col16]. col < 65536.
__global__ void k_fill(const int* __restrict__ ei, const float* __restrict__ ea,
                       const int* __restrict__ off, const int* __restrict__ rel,
                       unsigned* __restrict__ sorted) {
    int e = blockIdx.x * blockDim.x + threadIdx.x;
    if (e >= EE) return;
    int col = ei[e];
    int row = ei[EE + e];
    unsigned pk = ((unsigned)f2bf(ea[e]) << 16) | (unsigned)(col & 0xFFFF);
    sorted[off[row] + rel[e]] = pk;
}

// ---------------- ne_sum from CSR: 8 lanes per node, 4-way unroll ------------
__global__ void k_nesum(const float* __restrict__ x, const unsigned* __restrict__ sorted,
                        const int* __restrict__ off, float* __restrict__ ne_sum) {
    int gwave = (blockIdx.x * blockDim.x + threadIdx.x) >> 6;
    int lane = threadIdx.x & 63;
    int sub = lane >> 3;   // 8 nodes per wave
    int f = lane & 7;      // 8 features (7 x + 1 ea)
    int node = gwave * 8 + sub;
    if (node >= NN) return;
    int jb = off[node], je = off[node + 1];
    float a0 = 0.f, a1 = 0.f, a2 = 0.f, a3 = 0.f;
    int j = jb;
    for (; j + 4 <= je; j += 4) {
        unsigned p0 = sorted[j],     p1 = sorted[j + 1];
        unsigned p2 = sorted[j + 2], p3 = sorted[j + 3];
        a0 += (f < 7) ? x[(size_t)(p0 & 0xFFFFu) * 7 + f] : __uint_as_float(p0 & 0xFFFF0000u);
        a1 += (f < 7) ? x[(size_t)(p1 & 0xFFFFu) * 7 + f] : __uint_as_float(p1 & 0xFFFF0000u);
        a2 += (f < 7) ? x[(size_t)(p2 & 0xFFFFu) * 7 + f] : __uint_as_float(p2 & 0xFFFF0000u);
        a3 += (f < 7) ? x[(size_t)(p3 & 0xFFFFu) * 7 + f] : __uint_as_float(p3 & 0xFFFF0000u);
    }
    for (; j < je; j++) {
        unsigned p = sorted[j];
        a0 += (f < 7) ? x[(size_t)(p & 0xFFFFu) * 7 + f] : __uint_as_float(p & 0xFFFF0000u);
    }
    ne_sum[(size_t)node * 8 + f] = (a0 + a1) + (a2 + a3);
}

// ---------------- node pre: x_emb (fp32 + bf16 shadow) + FUSED x_agg_emb -----
__global__ __launch_bounds__(256) void k_node_pre(
        const float* __restrict__ x, const int* __restrict__ cnt,
        const float* __restrict__ ne_sum, const unsigned* __restrict__ degmax_u,
        const int* __restrict__ batch,
        const float* __restrict__ W_en, const float* __restrict__ b_en,
        const float* __restrict__ W_ene, const float* __restrict__ b_ene,
        const float* __restrict__ W_agg, const float* __restrict__ b_agg,
        float* __restrict__ x_emb, unsigned short* __restrict__ xh,
        float* __restrict__ xae) {
    __shared__ float sWen[7 * 64], sben[64];
    __shared__ float sWene[8 * 63], sbene[63];
    __shared__ float srow[4][64];
    for (int i = threadIdx.x; i < 7 * 64; i += 256) sWen[i] = W_en[i];
    for (int i = threadIdx.x; i < 64; i += 256) sben[i] = b_en[i];
    for (int i = threadIdx.x; i < 8 * 63; i += 256) sWene[i] = W_ene[i];
    for (int i = threadIdx.x; i < 63; i += 256) sbene[i] = b_ene[i];
    __syncthreads();
    int lane = threadIdx.x & 63;
    int slot = threadIdx.x >> 6;
    int wave = blockIdx.x * 4 + slot;
    int nw = gridDim.x * 4;
    float wagg[64];
#pragma unroll
    for (int k = 0; k < 64; k++) wagg[k] = W_agg[(size_t)k * 64 + lane];
    float bagg = b_agg[lane];
    for (int i = wave; i < NN; i += nw) {
        float acc = sben[lane];
#pragma unroll
        for (int k = 0; k < 7; k++) acc += x[(size_t)i * 7 + k] * sWen[k * 64 + lane];
        float xe = reluf(acc);
        x_emb[(size_t)i * 64 + lane] = xe;
        xh[(size_t)i * 64 + lane] = f2bf(xe);
        float c = (float)cnt[i]; if (c < 1.f) c = 1.f;
        float rc = 1.f / c;
        int oo = lane < 63 ? lane : 0;
        float4 n0 = *(const float4*)(ne_sum + (size_t)i * 8);
        float4 n1 = *(const float4*)(ne_sum + (size_t)i * 8 + 4);
        float na = sbene[oo];
        na += (n0.x * rc) * sWene[0 * 63 + oo];
        na += (n0.y * rc) * sWene[1 * 63 + oo];
        na += (n0.z * rc) * sWene[2 * 63 + oo];
        na += (n0.w * rc) * sWene[3 * 63 + oo];
        na += (n1.x * rc) * sWene[4 * 63 + oo];
        na += (n1.y * rc) * sWene[5 * 63 + oo];
        na += (n1.z * rc) * sWene[6 * 63 + oo];
        na += (n1.w * rc) * sWene[7 * 63 + oo];
        na = reluf(na);
        float dn = __uint_as_float(degmax_u[batch[i]]);
        float val = (lane < 63) ? na : dn;   // agg_in row, lane-distributed
        srow[slot][lane] = val;              // same-wave stage (k_mv64 idiom)
        const float* rp = &srow[slot][0];
        float a0 = bagg, a1 = 0.f;
#pragma unroll
        for (int kb = 0; kb < 64; kb += 8) {
            float4 x0 = *(const float4*)(rp + kb);
            float4 x1 = *(const float4*)(rp + kb + 4);
            a0 = fmaf(x0.x, wagg[kb + 0], a0); a1 = fmaf(x0.y, wagg[kb + 1], a1);
            a0 = fmaf(x0.z, wagg[kb + 2], a0); a1 = fmaf(x0.w, wagg[kb + 3], a1);
            a0 = fmaf(x1.x, wagg[kb + 4], a0); a1 = fmaf(x1.y, wagg[kb + 5], a1);
            a0 = fmaf(x1.z, wagg[kb + 6], a0); a1 = fmaf(x1.w, wagg[kb + 7], a1);
        }
        xae[(size_t)i * 64 + lane] = reluf(a0 + a1);
    }
}

// ---------------- fused K=128 matvec: out = relu([A|B] @ W + b) --------------
// r8 lesson: this kernel sits ~5 VGPRs below the (256,3) spill cliff (w[128]
// in registers). DO NOT add live state to the inner loop -- the r8 ndot
// fusion spilled w[] to scratch (VGPR 84, FETCH 727MB, 358us).
// GSUM=1 (final pass only): inline per-graph sums (batch-sorted run tracking).
// WRH=1: also emit bf16 shadow of the output row (next layer's gather).
template <int GSUM, int WRH>
__global__ __launch_bounds__(256, 3) void k_mv128(
        const float* __restrict__ inA, const float* __restrict__ inB,
        const float* __restrict__ W, const float* __restrict__ b,
        float* __restrict__ out, unsigned short* __restrict__ outh, int nwaves,
        const int* __restrict__ batch, float* __restrict__ g_sum) {
    __shared__ float sbuf[4][2][128];
    int slot = threadIdx.x >> 6;
    int gwave = (blockIdx.x * blockDim.x + threadIdx.x) >> 6;
    int lane = threadIdx.x & 63;
    int per = (NN + nwaves - 1) / nwaves;
    int n0 = gwave * per;
    int n1 = n0 + per; if (n1 > NN) n1 = NN;
    if (n0 >= n1) return;
    float w[128];
#pragma unroll
    for (int k = 0; k < 128; k++) w[k] = W[(size_t)k * 64 + lane];
    float bias = b[lane];
    sbuf[slot][0][lane]      = inA[(size_t)n0 * 64 + lane];
    sbuf[slot][0][64 + lane] = inB[(size_t)n0 * 64 + lane];
    int cntn = n1 - n0;
    float gacc = 0.f;
    int curb = GSUM ? batch[n0] : 0;
    for (int i = 0; i < cntn; i++) {
        int n = n0 + i;
        float vA = 0.f, vB = 0.f;
        if (i + 1 < cntn) {
            vA = inA[(size_t)(n + 1) * 64 + lane];
            vB = inB[(size_t)(n + 1) * 64 + lane];
        }
        const float* bufp = &sbuf[slot][i & 1][0];
        float a0 = 0.f, a1 = 0.f;
#pragma unroll
        for (int kb = 0; kb < 128; kb += 8) {
            float4 x0 = *(const float4*)(bufp + kb);
            float4 x1 = *(const float4*)(bufp + kb + 4);
            a0 = fmaf(x0.x, w[kb + 0], a0); a1 = fmaf(x0.y, w[kb + 1], a1);
            a0 = fmaf(x0.z, w[kb + 2], a0); a1 = fmaf(x0.w, w[kb + 3], a1);
            a0 = fmaf(x1.x, w[kb + 4], a0); a1 = fmaf(x1.y, w[kb + 5], a1);
            a0 = fmaf(x1.z, w[kb + 6], a0); a1 = fmaf(x1.w, w[kb + 7], a1);
        }
        float r = reluf(a0 + a1 + bias);
        out[(size_t)n * 64 + lane] = r;
        if (WRH) outh[(size_t)n * 64 + lane] = f2bf(r);
        if (GSUM) {
            int bb = batch[n];
            if (bb != curb) {
                unsafeAtomicAdd(&g_sum[curb * 64 + lane], gacc);
                gacc = 0.f; curb = bb;
            }
            gacc += r;
        }
        if (i + 1 < cntn) {
            sbuf[slot][(i + 1) & 1][lane]      = vA;
            sbuf[slot][(i + 1) & 1][64 + lane] = vB;
        }
    }
    if (GSUM) unsafeAtomicAdd(&g_sum[curb * 64 + lane], gacc);
}

// -------- layer aggregation: x_agg = mean_j ea_j * xemb[col_j] ---------------
// r0-proven 8-wide inner structure; r4-proven one node per wave;
// r6-proven bf16 shadow gathers; r7-kept 4B packed edge records.
__global__ __launch_bounds__(256) void k_layer_agg(
        const unsigned short* __restrict__ xembh, const int* __restrict__ off,
        const int* __restrict__ cnt, const unsigned* __restrict__ sorted,
        float* __restrict__ xagg) {
    int lane = threadIdx.x & 63;
    int i = (blockIdx.x * blockDim.x + threadIdx.x) >> 6;   // node == wave id
    if (i >= NN) return;
    {
        int jb = off[i], je = off[i + 1];
        float a0 = 0.f, a1 = 0.f, a2 = 0.f, a3 = 0.f;
        float a4 = 0.f, a5 = 0.f, a6 = 0.f, a7 = 0.f;
        int j = jb;
        for (; j + 8 <= je; j += 8) {
            unsigned p0 = sorted[j + 0], p1 = sorted[j + 1];
            unsigned p2 = sorted[j + 2], p3 = sorted[j + 3];
            unsigned p4 = sorted[j + 4], p5 = sorted[j + 5];
            unsigned p6 = sorted[j + 6], p7 = sorted[j + 7];
            a0 = fmaf(__uint_as_float(p0 & 0xFFFF0000u), bf2f(xembh[(size_t)(p0 & 0xFFFFu) * 64 + lane]), a0);
            a1 = fmaf(__uint_as_float(p1 & 0xFFFF0000u), bf2f(xembh[(size_t)(p1 & 0xFFFFu) * 64 + lane]), a1);
            a2 = fmaf(__uint_as_float(p2 & 0xFFFF0000u), bf2f(xembh[(size_t)(p2 & 0xFFFFu) * 64 + lane]), a2);
            a3 = fmaf(__uint_as_float(p3 & 0xFFFF0000u), bf2f(xembh[(size_t)(p3 & 0xFFFFu) * 64 + lane]), a3);
            a4 = fmaf(__uint_as_float(p4 & 0xFFFF0000u), bf2f(xembh[(size_t)(p4 & 0xFFFFu) * 64 + lane]), a4);
            a5 = fmaf(__uint_as_float(p5 & 0xFFFF0000u), bf2f(xembh[(size_t)(p5 & 0xFFFFu) * 64 + lane]), a5);
            a6 = fmaf(__uint_as_float(p6 & 0xFFFF0000u), bf2f(xembh[(size_t)(p6 & 0xFFFFu) * 64 + lane]), a6);
            a7 = fmaf(__uint_as_float(p7 & 0xFFFF0000u), bf2f(xembh[(size_t)(p7 & 0xFFFFu) * 64 + lane]), a7);
        }
        if (j < je) {   // masked tail: 1-7 edges, all gathers independent
            int jl = je - 1;
            unsigned p0 = sorted[j + 0];
            unsigned p1 = sorted[min(j + 1, jl)];
            unsigned p2 = sorted[min(j + 2, jl)];
            unsigned p3 = sorted[min(j + 3, jl)];
            unsigned p4 = sorted[min(j + 4, jl)];
            unsigned p5 = sorted[min(j + 5, jl)];
            unsigned p6 = sorted[min(j + 6, jl)];
            unsigned p7 = sorted[min(j + 7, jl)];
            float s0 = __uint_as_float(p0 & 0xFFFF0000u);
            float s1 = (j + 1 < je) ? __uint_as_float(p1 & 0xFFFF0000u) : 0.f;
            float s2 = (j + 2 < je) ? __uint_as_float(p2 & 0xFFFF0000u) : 0.f;
            float s3 = (j + 3 < je) ? __uint_as_float(p3 & 0xFFFF0000u) : 0.f;
            float s4 = (j + 4 < je) ? __uint_as_float(p4 & 0xFFFF0000u) : 0.f;
            float s5 = (j + 5 < je) ? __uint_as_float(p5 & 0xFFFF0000u) : 0.f;
            float s6 = (j + 6 < je) ? __uint_as_float(p6 & 0xFFFF0000u) : 0.f;
            float s7 = (j + 7 < je) ? __uint_as_float(p7 & 0xFFFF0000u) : 0.f;
            a0 = fmaf(s0, bf2f(xembh[(size_t)(p0 & 0xFFFFu) * 64 + lane]), a0);
            a1 = fmaf(s1, bf2f(xembh[(size_t)(p1 & 0xFFFFu) * 64 + lane]), a1);
            a2 = fmaf(s2, bf2f(xembh[(size_t)(p2 & 0xFFFFu) * 64 + lane]), a2);
            a3 = fmaf(s3, bf2f(xembh[(size_t)(p3 & 0xFFFFu) * 64 + lane]), a3);
            a4 = fmaf(s4, bf2f(xembh[(size_t)(p4 & 0xFFFFu) * 64 + lane]), a4);
            a5 = fmaf(s5, bf2f(xembh[(size_t)(p5 & 0xFFFFu) * 64 + lane]), a5);
            a6 = fmaf(s6, bf2f(xembh[(size_t)(p6 & 0xFFFFu) * 64 + lane]), a6);
            a7 = fmaf(s7, bf2f(xembh[(size_t)(p7 & 0xFFFFu) * 64 + lane]), a7);
        }
        float acc = ((a0 + a1) + (a2 + a3)) + ((a4 + a5) + (a6 + a7));
        float c = (float)cnt[i]; if (c < 1.f) c = 1.f;
        xagg[(size_t)i * 64 + lane] = acc * (1.f / c);
    }
}

// ------- graph embedding: g_agg = mean @ W_g + b_g, then fused readout dot ---
__global__ void k_graph_emb(const float* __restrict__ g_sum, const int* __restrict__ g_cnt,
                            const float* __restrict__ W_g, const float* __restrict__ b_g,
                            const float* __restrict__ W_r, float* __restrict__ dotA) {
    __shared__ float sin[4 * 64];
    int lane = threadIdx.x & 63;
    int slot = threadIdx.x >> 6;
    int g = blockIdx.x * 4 + slot;
    if (g >= GG) return;
    float c = (float)g_cnt[g]; if (c < 1.f) c = 1.f;
    sin[slot * 64 + lane] = g_sum[g * 64 + lane] * (1.f / c);
    __syncthreads();
    float acc = b_g[lane];
    for (int k = 0; k < 64; k++) acc += sin[slot * 64 + k] * W_g[k * 64 + lane];
    float v = reluf(acc) * W_r[lane];
#pragma unroll
    for (int d = 1; d < 64; d <<= 1) v += __shfl_xor(v, d, 64);
    if (lane == 0) dotA[g] = v;
}

// ---------------- readout: q = dotA[batch] + relu(x_emb) @ W_r[64:] + b_r ----
__global__ void k_readout(const float* __restrict__ dotA, const float* __restrict__ xemb,
                          const int* __restrict__ batch,
                          const float* __restrict__ W_r, const float* __restrict__ b_r,
                          float* __restrict__ out) {
    int i = blockIdx.x * blockDim.x + threadIdx.x;
    if (i >= NN) return;
    int b = batch[i];
    float acc = b_r[0] + dotA[b];
    const float* xe = xemb + (size_t)i * 64;
#pragma unroll 8
    for (int k = 0; k < 64; k++) acc += reluf(xe[k]) * W_r[64 + k];
    out[i] = acc;
}

extern "C" void kernel_launch(void* const* d_in, const int* in_sizes, int n_in,
                              void* d_out, int out_size, void* d_ws, size_t ws_size,
                              hipStream_t stream) {
    const float* x      = (const float*)d_in[0];
    const int*   ei     = (const int*)d_in[1];
    const float* ea     = (const float*)d_in[2];
    const int*   batch  = (const int*)d_in[3];
    const float* degree = (const float*)d_in[4];
    const float* W_en  = (const float*)d_in[6];
    const float* b_en  = (const float*)d_in[7];
    const float* W_ene = (const float*)d_in[8];
    const float* b_ene = (const float*)d_in[9];
    const float* W_agg = (const float*)d_in[10];
    const float* b_agg = (const float*)d_in[11];
    const float* Wm    = (const float*)d_in[12];
    const float* bm    = (const float*)d_in[13];
    const float* Wu    = (const float*)d_in[14];
    const float* bu    = (const float*)d_in[15];
    const float* W_g   = (const float*)d_in[16];
    const float* b_g   = (const float*)d_in[17];
    const float* W_r   = (const float*)d_in[18];
    const float* b_r   = (const float*)d_in[19];
    float* out = (float*)d_out;

    // workspace layout (4B element offsets); zeroed region first
    char* ws = (char*)d_ws;
    size_t o = 0;
    int*      cnt      = (int*)(ws + o * 4);      o += NN;
    unsigned* degmax_u = (unsigned*)(ws + o * 4); o += GG;
    float*    g_sum    = (float*)(ws + o * 4);    o += GG * 64;
    int*      g_cnt    = (int*)(ws + o * 4);      o += GG;
    size_t zero_bytes = o * 4;
    int*      off      = (int*)(ws + o * 4);      o += NN + 1;
    int*      bsum     = (int*)(ws + o * 4);      o += 64;
    int*      rel      = (int*)(ws + o * 4);      o += EE;
    float*    ne_sum   = (float*)(ws + o * 4);    o += (size_t)NN * 8;
    unsigned* sorted   = (unsigned*)(ws + o * 4); o += EE;          // packed 4B/edge
    unsigned short* xh = (unsigned short*)(ws + o * 4); o += (size_t)NN * 32;  // bf16 shadow
    float*    xae      = (float*)(ws + o * 4);    o += (size_t)NN * 64;
    float*    xA       = (float*)(ws + o * 4);    o += (size_t)NN * 64;
    float*    xB       = (float*)(ws + o * 4);    o += (size_t)NN * 64;
    float*    xagg     = (float*)(ws + o * 4);    o += (size_t)NN * 64;
    float*    mbuf     = (float*)(ws + o * 4);    o += (size_t)NN * 64;
    float*    dotA     = (float*)(ws + o * 4);    o += GG;

    hipMemsetAsync(d_ws, 0, zero_bytes, stream);

    const int NB_SCAN = 49;        // ceil(50001/1024)
    const int MV_BLOCKS = 768;     // 3072 waves = 3/SIMD resident, 17 nodes/wave
    const int MV_WAVES = MV_BLOCKS * 4;
    k_count<<<(EE + 255) / 256, 256, 0, stream>>>(ei, cnt, rel);
    k_scan1<<<NB_SCAN, 256, 0, stream>>>(cnt, off, bsum, batch, degree, degmax_u, g_cnt);
    k_scan3<<<(NN + 256) / 256, 256, 0, stream>>>(off, bsum);
    k_fill<<<(EE + 255) / 256, 256, 0, stream>>>(ei, ea, off, rel, sorted);
    k_nesum<<<((NN + 7) / 8 * 64 + 255) / 256, 256, 0, stream>>>(x, sorted, off, ne_sum);
    // node pre produces x_agg_emb directly (W_agg fused) + bf16 shadow of x_emb
    k_node_pre<<<1024, 256, 0, stream>>>(x, cnt, ne_sum, degmax_u, batch,
                                         W_en, b_en, W_ene, b_ene, W_agg, b_agg,
                                         xA, xh, xae);
    const float* cur = xA;
    float* nxt = xB;
    const int AGG_BLOCKS = (NN * 64 + 255) / 256;   // one node per wave
    for (int l = 0; l < LL; l++) {
        const float* WmL = Wm + (size_t)l * 128 * 64;
        const float* WuL = Wu + (size_t)l * 128 * 64;
        k_layer_agg<<<AGG_BLOCKS, 256, 0, stream>>>(xh, off, cnt, sorted, xagg);
        // m = relu([xagg|xae] @ Wm + bm)   -- single fused K=128 pass
        k_mv128<0, 0><<<MV_BLOCKS, 256, 0, stream>>>(xagg, xae, WmL, bm + l * 64,
                                                     mbuf, nullptr, MV_WAVES, nullptr, nullptr);
        // x' = relu([xemb|m] @ Wu + bu)    -- single fused K=128 pass
        if (l < LL - 1) {
            // also refresh the bf16 shadow for the next layer's gather
            k_mv128<0, 1><<<MV_BLOCKS, 256, 0, stream>>>(cur, mbuf, WuL, bu + l * 64,
                                                         nxt, xh, MV_WAVES, nullptr, nullptr);
        } else {
            // final layer: fuse graph-sum accumulation (no gather follows -> no shadow)
            k_mv128<1, 0><<<MV_BLOCKS, 256, 0, stream>>>(cur, mbuf, WuL, bu + l * 64,
                                                         nxt, nullptr, MV_WAVES, batch, g_sum);
        }
        float* t = (float*)cur; cur = nxt; nxt = t;
    }
    k_graph_emb<<<16, 256, 0, stream>>>(g_sum, g_cnt, W_g, b_g, W_r, dotA);
    k_readout<<<(NN + 255) / 256, 256, 0, stream>>>(dotA, cur, batch, W_r, b_r, out);
}